// Round 1
// baseline (633.815 us; speedup 1.0000x reference)
//
#include <hip/hip_runtime.h>
#include <math.h>

#define L_ 2048
#define CDIM 384
#define DI 768
#define DSTATE 16
#define RNK 24

struct DirParams { const float *cw, *cb, *xpw, *dtw, *dtb, *Alog, *D; };
struct AllParams { DirParams p[3]; };

__device__ __forceinline__ int pmap(int dir, int l) {
  if (dir == 0) return l;
  if (dir == 1) return 2047 - l;
  return ((l & 7) << 8) + (l >> 3);   // slice perm: (l%8)*256 + l/8
}

// ---------------- LayerNorm: x (C,L) -> xn (L,C) ----------------
__global__ __launch_bounds__(256) void k_ln(const float* __restrict__ x,
    const float* __restrict__ g, const float* __restrict__ b,
    float* __restrict__ xn) {
  int l = blockIdx.x, tid = threadIdx.x;
  __shared__ float vals[CDIM];
  __shared__ float red[4];
  __shared__ float mu_s, rstd_s;
  float s = 0.f;
  for (int c = tid; c < CDIM; c += 256) {
    float v = x[(size_t)c * L_ + l];
    vals[c] = v; s += v;
  }
  for (int o = 32; o; o >>= 1) s += __shfl_down(s, o);
  int wid = tid >> 6, lane = tid & 63;
  if (lane == 0) red[wid] = s;
  __syncthreads();
  if (tid == 0) mu_s = (red[0] + red[1] + red[2] + red[3]) / (float)CDIM;
  __syncthreads();
  float mu = mu_s;
  float s2 = 0.f;
  for (int c = tid; c < CDIM; c += 256) { float v = vals[c] - mu; s2 += v * v; }
  for (int o = 32; o; o >>= 1) s2 += __shfl_down(s2, o);
  if (lane == 0) red[wid] = s2;
  __syncthreads();
  if (tid == 0) rstd_s = rsqrtf((red[0] + red[1] + red[2] + red[3]) / (float)CDIM + 1e-5f);
  __syncthreads();
  float rstd = rstd_s;
  for (int c = tid; c < CDIM; c += 256)
    xn[(size_t)l * CDIM + c] = (vals[c] - mu) * rstd * g[c] + b[c];
}

// ---------------- Tiled fp32 GEMM: C[m][n] = sum_k A[m][k]*W[n][k] ----------------
// TRANS_OUT: write Cout[n*M+m] (+resid) instead of Cout[m*N+n]
template <bool TRANS_OUT>
__global__ __launch_bounds__(256) void k_gemm(const float* __restrict__ A,
    const float* __restrict__ W, float* __restrict__ Cout,
    const float* __restrict__ resid, int M, int N, int K) {
  __shared__ float As[16][65];
  __shared__ float Bs[16][65];
  int m0 = blockIdx.y * 64, n0 = blockIdx.x * 64;
  int tid = threadIdx.x;
  int lr = tid >> 2;           // 0..63
  int lk = (tid & 3) << 2;     // 0,4,8,12
  int tm = (tid >> 4) << 2;    // 0..60
  int tn = (tid & 15) << 2;    // 0..60
  float acc[4][4] = {};
  for (int k0 = 0; k0 < K; k0 += 16) {
    float4 a = *(const float4*)(A + (size_t)(m0 + lr) * K + k0 + lk);
    float4 w = *(const float4*)(W + (size_t)(n0 + lr) * K + k0 + lk);
    As[lk + 0][lr] = a.x; As[lk + 1][lr] = a.y; As[lk + 2][lr] = a.z; As[lk + 3][lr] = a.w;
    Bs[lk + 0][lr] = w.x; Bs[lk + 1][lr] = w.y; Bs[lk + 2][lr] = w.z; Bs[lk + 3][lr] = w.w;
    __syncthreads();
#pragma unroll
    for (int kk = 0; kk < 16; ++kk) {
      float av[4], bv[4];
#pragma unroll
      for (int i = 0; i < 4; ++i) av[i] = As[kk][tm + i];
#pragma unroll
      for (int j = 0; j < 4; ++j) bv[j] = Bs[kk][tn + j];
#pragma unroll
      for (int i = 0; i < 4; ++i)
#pragma unroll
        for (int j = 0; j < 4; ++j) acc[i][j] = fmaf(av[i], bv[j], acc[i][j]);
    }
    __syncthreads();
  }
  if (!TRANS_OUT) {
#pragma unroll
    for (int i = 0; i < 4; ++i)
#pragma unroll
      for (int j = 0; j < 4; ++j)
        Cout[(size_t)(m0 + tm + i) * N + n0 + tn + j] = acc[i][j];
  } else {
#pragma unroll
    for (int i = 0; i < 4; ++i)
#pragma unroll
      for (int j = 0; j < 4; ++j) {
        size_t idx = (size_t)(n0 + tn + j) * M + (m0 + tm + i);
        Cout[idx] = acc[i][j] + resid[idx];
      }
  }
}

// ---------------- Conv(4, causal, depthwise) + SiLU, per direction ----------------
// xz is (L,1536) token-major; xc_all[dir] is (L,768)
__global__ __launch_bounds__(256) void k_conv(const float* __restrict__ xz,
    float* __restrict__ xc_all, AllParams P) {
  int dir = blockIdx.y;
  int bx = blockIdx.x;
  int l = bx / 3, dch = bx % 3;
  int d = dch * 256 + threadIdx.x;
  const DirParams& dp = P.p[dir];
  float4 w = *(const float4*)(dp.cw + d * 4);
  float wv[4] = {w.x, w.y, w.z, w.w};
  float acc = dp.cb[d];
#pragma unroll
  for (int k = 0; k < 4; ++k) {
    int ls = l - 3 + k;
    if (ls >= 0) acc = fmaf(wv[k], xz[(size_t)pmap(dir, ls) * 1536 + d], acc);
  }
  float sv = acc / (1.f + __expf(-acc));
  xc_all[(size_t)dir * (L_ * DI) + (size_t)l * DI + d] = sv;
}

// ---------------- x-proj (768->56) + dt-proj (24->768) + softplus ----------------
__global__ __launch_bounds__(256) void k_xproj(const float* __restrict__ xc_all,
    float* __restrict__ dt_all, float* __restrict__ B_all, float* __restrict__ C_all,
    AllParams P) {
  int dir = blockIdx.y;
  int l0 = blockIdx.x * 16;
  const DirParams& dp = P.p[dir];
  const float* xc = xc_all + (size_t)dir * (L_ * DI) + (size_t)l0 * DI;
  __shared__ float xr[16 * 769];
  __shared__ float dbls[16 * 56];
  int tid = threadIdx.x;
  for (int idx = tid; idx < 16 * DI; idx += 256) {
    int t = idx / DI, c = idx - t * DI;
    xr[t * 769 + c] = xc[idx];
  }
  __syncthreads();
  {
    int ti = tid & 15, jg = tid >> 4;
    for (int j0 = 0; j0 < 64; j0 += 16) {
      int j = j0 + jg;
      if (j < 56) {
        float acc = 0.f;
        const float* wrow = dp.xpw + (size_t)j * DI;
        const float* xrow = xr + ti * 769;
        for (int c = 0; c < DI; c += 4) {
          float4 w4 = *(const float4*)(wrow + c);
          acc = fmaf(w4.x, xrow[c], acc);
          acc = fmaf(w4.y, xrow[c + 1], acc);
          acc = fmaf(w4.z, xrow[c + 2], acc);
          acc = fmaf(w4.w, xrow[c + 3], acc);
        }
        dbls[ti * 56 + j] = acc;
      }
    }
  }
  __syncthreads();
  int tok = tid >> 4, dml = tid & 15;
  const float* db = dbls + tok * 56;
  for (int k = 0; k < 48; ++k) {
    int d = dml + k * 16;
    float acc = dp.dtb[d];
    const float* wr = dp.dtw + d * RNK;
#pragma unroll
    for (int r = 0; r < RNK; r += 4) {
      float4 w4 = *(const float4*)(wr + r);
      acc = fmaf(w4.x, db[r], acc);
      acc = fmaf(w4.y, db[r + 1], acc);
      acc = fmaf(w4.z, db[r + 2], acc);
      acc = fmaf(w4.w, db[r + 3], acc);
    }
    float sp = fmaxf(acc, 0.f) + log1pf(__expf(-fabsf(acc)));
    dt_all[(size_t)dir * (L_ * DI) + (size_t)(l0 + tok) * DI + d] = sp;
  }
  {
    int s = dml;
    B_all[dir * (L_ * DSTATE) + (l0 + tok) * DSTATE + s] = db[RNK + s];
    C_all[dir * (L_ * DSTATE) + (l0 + tok) * DSTATE + s] = db[RNK + DSTATE + s];
  }
}

// ---------------- Selective scan: thread per (d,s), LDS-chunked over L ----------------
__global__ __launch_bounds__(256) void k_scan(const float* __restrict__ dt_all,
    const float* __restrict__ xc_all, const float* __restrict__ B_all,
    const float* __restrict__ C_all, float* __restrict__ y_all, AllParams P) {
  int dir = blockIdx.y;
  int d0 = blockIdx.x * 16;
  int tid = threadIdx.x;
  int dl = tid >> 4, s = tid & 15;
  const float* dt = dt_all + (size_t)dir * (L_ * DI);
  const float* xc = xc_all + (size_t)dir * (L_ * DI);
  const float* Bp = B_all + dir * (L_ * DSTATE);
  const float* Cp = C_all + dir * (L_ * DSTATE);
  float* yp = y_all + (size_t)dir * (L_ * DI);
  float Aval = -__expf(P.p[dir].Alog[(d0 + dl) * DSTATE + s]);
  __shared__ float dts[64 * 16], xcs[64 * 16], Bsh[64 * 16], Csh[64 * 16], ysh[64 * 16];
  float h = 0.f;
  int li = tid >> 4, lj = tid & 15;
  for (int l0 = 0; l0 < L_; l0 += 64) {
#pragma unroll
    for (int r = 0; r < 4; ++r) {
      int i = li + r * 16;
      dts[i * 16 + lj] = dt[(size_t)(l0 + i) * DI + d0 + lj];
      xcs[i * 16 + lj] = xc[(size_t)(l0 + i) * DI + d0 + lj];
    }
#pragma unroll
    for (int r = 0; r < 4; ++r) {
      int idx = tid + r * 256;
      Bsh[idx] = Bp[l0 * DSTATE + idx];
      Csh[idx] = Cp[l0 * DSTATE + idx];
    }
    __syncthreads();
    for (int ii = 0; ii < 64; ++ii) {
      float dtv = dts[ii * 16 + dl];
      float xv = xcs[ii * 16 + dl];
      float a = __expf(dtv * Aval);
      h = fmaf(a, h, dtv * xv * Bsh[ii * 16 + s]);
      float p = h * Csh[ii * 16 + s];
      p += __shfl_xor(p, 8);
      p += __shfl_xor(p, 4);
      p += __shfl_xor(p, 2);
      p += __shfl_xor(p, 1);
      if (s == 0) ysh[ii * 16 + dl] = p;
    }
    __syncthreads();
#pragma unroll
    for (int r = 0; r < 4; ++r) {
      int i = li + r * 16;
      yp[(size_t)(l0 + i) * DI + d0 + lj] = ysh[i * 16 + lj];
    }
    __syncthreads();
  }
}

// ---------------- Gate + combine 3 directions -> ysum (L,768) ----------------
__global__ __launch_bounds__(256) void k_gate(const float* __restrict__ y_all,
    const float* __restrict__ xc_all, const float* __restrict__ xz,
    float* __restrict__ ysum, AllParams P) {
  int l = blockIdx.x;
  int lb = 2047 - l;
  int ls = ((l & 255) << 3) + (l >> 8);   // inv of slice perm
  const size_t DSZ = (size_t)L_ * DI;
  for (int dd = threadIdx.x; dd < DI; dd += 256) {
    float yf = y_all[0 * DSZ + (size_t)l * DI + dd] + xc_all[0 * DSZ + (size_t)l * DI + dd] * P.p[0].D[dd];
    float yb = y_all[1 * DSZ + (size_t)lb * DI + dd] + xc_all[1 * DSZ + (size_t)lb * DI + dd] * P.p[1].D[dd];
    float ys = y_all[2 * DSZ + (size_t)ls * DI + dd] + xc_all[2 * DSZ + (size_t)ls * DI + dd] * P.p[2].D[dd];
    float z = xz[(size_t)l * 1536 + DI + dd];
    ysum[(size_t)l * DI + dd] = (yf + yb + ys) * (z / (1.f + __expf(-z)));
  }
}

extern "C" void kernel_launch(void* const* d_in, const int* in_sizes, int n_in,
                              void* d_out, int out_size, void* d_ws, size_t ws_size,
                              hipStream_t stream) {
  const float* x = (const float*)d_in[0];
  const float* ln_g = (const float*)d_in[1];
  const float* ln_b = (const float*)d_in[2];
  const float* in_proj_w = (const float*)d_in[3];
  const float* out_proj_w = (const float*)d_in[4];
  AllParams P;
  for (int dir = 0; dir < 3; ++dir) {
    int base = 5 + dir * 7;
    P.p[dir].cw  = (const float*)d_in[base + 0];
    P.p[dir].cb  = (const float*)d_in[base + 1];
    P.p[dir].xpw = (const float*)d_in[base + 2];
    P.p[dir].dtw = (const float*)d_in[base + 3];
    P.p[dir].dtb = (const float*)d_in[base + 4];
    P.p[dir].Alog= (const float*)d_in[base + 5];
    P.p[dir].D   = (const float*)d_in[base + 6];
  }
  float* ws = (float*)d_ws;
  const size_t SZ_XN = (size_t)L_ * CDIM;        // 786432
  const size_t SZ_XZ = (size_t)L_ * 1536;        // 3145728
  const size_t SZ_DI = (size_t)L_ * DI;          // 1572864
  const size_t SZ_BS = (size_t)L_ * DSTATE;      // 32768
  float* xn    = ws;
  float* xz    = xn + SZ_XN;
  float* xc_a  = xz + SZ_XZ;                     // 3 dirs
  float* dt_a  = xc_a + 3 * SZ_DI;
  float* B_a   = dt_a + 3 * SZ_DI;
  float* C_a   = B_a + 3 * SZ_BS;
  float* y_a   = C_a + 3 * SZ_BS;
  float* ysum  = y_a + 3 * SZ_DI;

  k_ln<<<L_, 256, 0, stream>>>(x, ln_g, ln_b, xn);
  k_gemm<false><<<dim3(1536 / 64, L_ / 64), 256, 0, stream>>>(
      xn, in_proj_w, xz, nullptr, L_, 1536, CDIM);
  k_conv<<<dim3(L_ * 3, 3), 256, 0, stream>>>(xz, xc_a, P);
  k_xproj<<<dim3(L_ / 16, 3), 256, 0, stream>>>(xc_a, dt_a, B_a, C_a, P);
  k_scan<<<dim3(DI / 16, 3), 256, 0, stream>>>(dt_a, xc_a, B_a, C_a, y_a, P);
  k_gate<<<L_, 256, 0, stream>>>(y_a, xc_a, xz, ysum, P);
  k_gemm<true><<<dim3(CDIM / 64, L_ / 64), 256, 0, stream>>>(
      ysum, out_proj_w, (float*)d_out, x, L_, CDIM, DI);
}

// Round 2
// 338.490 us; speedup vs baseline: 1.8725x; 1.8725x over previous
//
#include <hip/hip_runtime.h>
#include <math.h>

#define L_ 2048
#define CDIM 384
#define DI 768
#define DSTATE 16
#define RNK 24
#define NCH 16
#define CH 128

struct DirParams { const float *cw, *cb, *xpw, *dtw, *dtb, *Alog, *D; };
struct AllParams { DirParams p[3]; };

__device__ __forceinline__ int pmap(int dir, int l) {
  if (dir == 0) return l;
  if (dir == 1) return 2047 - l;
  return ((l & 7) << 8) + (l >> 3);   // slice perm: (l%8)*256 + l/8
}

// ---------------- LayerNorm: x (C,L) -> xn (L,C) ----------------
__global__ __launch_bounds__(256) void k_ln(const float* __restrict__ x,
    const float* __restrict__ g, const float* __restrict__ b,
    float* __restrict__ xn) {
  int l = blockIdx.x, tid = threadIdx.x;
  __shared__ float vals[CDIM];
  __shared__ float red[4];
  __shared__ float mu_s, rstd_s;
  float s = 0.f;
  for (int c = tid; c < CDIM; c += 256) {
    float v = x[(size_t)c * L_ + l];
    vals[c] = v; s += v;
  }
  for (int o = 32; o; o >>= 1) s += __shfl_down(s, o);
  int wid = tid >> 6, lane = tid & 63;
  if (lane == 0) red[wid] = s;
  __syncthreads();
  if (tid == 0) mu_s = (red[0] + red[1] + red[2] + red[3]) / (float)CDIM;
  __syncthreads();
  float mu = mu_s;
  float s2 = 0.f;
  for (int c = tid; c < CDIM; c += 256) { float v = vals[c] - mu; s2 += v * v; }
  for (int o = 32; o; o >>= 1) s2 += __shfl_down(s2, o);
  if (lane == 0) red[wid] = s2;
  __syncthreads();
  if (tid == 0) rstd_s = rsqrtf((red[0] + red[1] + red[2] + red[3]) / (float)CDIM + 1e-5f);
  __syncthreads();
  float rstd = rstd_s;
  for (int c = tid; c < CDIM; c += 256)
    xn[(size_t)l * CDIM + c] = (vals[c] - mu) * rstd * g[c] + b[c];
}

// ---------------- Tiled fp32 GEMM: C[m][n] = sum_k A[m][k]*W[n][k] ----------------
template <bool TRANS_OUT>
__global__ __launch_bounds__(256) void k_gemm(const float* __restrict__ A,
    const float* __restrict__ W, float* __restrict__ Cout,
    const float* __restrict__ resid, int M, int N, int K) {
  __shared__ float As[16][65];
  __shared__ float Bs[16][65];
  int m0 = blockIdx.y * 64, n0 = blockIdx.x * 64;
  int tid = threadIdx.x;
  int lr = tid >> 2;           // 0..63
  int lk = (tid & 3) << 2;     // 0,4,8,12
  int tm = (tid >> 4) << 2;    // 0..60
  int tn = (tid & 15) << 2;    // 0..60
  float acc[4][4] = {};
  for (int k0 = 0; k0 < K; k0 += 16) {
    float4 a = *(const float4*)(A + (size_t)(m0 + lr) * K + k0 + lk);
    float4 w = *(const float4*)(W + (size_t)(n0 + lr) * K + k0 + lk);
    As[lk + 0][lr] = a.x; As[lk + 1][lr] = a.y; As[lk + 2][lr] = a.z; As[lk + 3][lr] = a.w;
    Bs[lk + 0][lr] = w.x; Bs[lk + 1][lr] = w.y; Bs[lk + 2][lr] = w.z; Bs[lk + 3][lr] = w.w;
    __syncthreads();
#pragma unroll
    for (int kk = 0; kk < 16; ++kk) {
      float av[4], bv[4];
#pragma unroll
      for (int i = 0; i < 4; ++i) av[i] = As[kk][tm + i];
#pragma unroll
      for (int j = 0; j < 4; ++j) bv[j] = Bs[kk][tn + j];
#pragma unroll
      for (int i = 0; i < 4; ++i)
#pragma unroll
        for (int j = 0; j < 4; ++j) acc[i][j] = fmaf(av[i], bv[j], acc[i][j]);
    }
    __syncthreads();
  }
  if (!TRANS_OUT) {
#pragma unroll
    for (int i = 0; i < 4; ++i)
#pragma unroll
      for (int j = 0; j < 4; ++j)
        Cout[(size_t)(m0 + tm + i) * N + n0 + tn + j] = acc[i][j];
  } else {
#pragma unroll
    for (int i = 0; i < 4; ++i)
#pragma unroll
      for (int j = 0; j < 4; ++j) {
        size_t idx = (size_t)(n0 + tn + j) * M + (m0 + tm + i);
        Cout[idx] = acc[i][j] + resid[idx];
      }
  }
}

// ---------------- Conv(4, causal, depthwise) + SiLU, per direction ----------------
__global__ __launch_bounds__(256) void k_conv(const float* __restrict__ xz,
    float* __restrict__ xc_all, AllParams P) {
  int dir = blockIdx.y;
  int bx = blockIdx.x;
  int l = bx / 3, dch = bx % 3;
  int d = dch * 256 + threadIdx.x;
  const DirParams& dp = P.p[dir];
  float4 w = *(const float4*)(dp.cw + d * 4);
  float wv[4] = {w.x, w.y, w.z, w.w};
  float acc = dp.cb[d];
#pragma unroll
  for (int k = 0; k < 4; ++k) {
    int ls = l - 3 + k;
    if (ls >= 0) acc = fmaf(wv[k], xz[(size_t)pmap(dir, ls) * 1536 + d], acc);
  }
  float sv = acc / (1.f + __expf(-acc));
  xc_all[(size_t)dir * (L_ * DI) + (size_t)l * DI + d] = sv;
}

// ---------------- x-proj (768->56) + dt-proj (24->768) + softplus ----------------
__global__ __launch_bounds__(256) void k_xproj(const float* __restrict__ xc_all,
    float* __restrict__ dt_all, float* __restrict__ B_all, float* __restrict__ C_all,
    AllParams P) {
  int dir = blockIdx.y;
  int l0 = blockIdx.x * 16;
  const DirParams& dp = P.p[dir];
  const float* xc = xc_all + (size_t)dir * (L_ * DI) + (size_t)l0 * DI;
  __shared__ float xr[16 * 769];
  __shared__ float dbls[16 * 56];
  int tid = threadIdx.x;
  for (int idx = tid; idx < 16 * DI; idx += 256) {
    int t = idx / DI, c = idx - t * DI;
    xr[t * 769 + c] = xc[idx];
  }
  __syncthreads();
  {
    int ti = tid & 15, jg = tid >> 4;
    for (int j0 = 0; j0 < 64; j0 += 16) {
      int j = j0 + jg;
      if (j < 56) {
        float acc = 0.f;
        const float* wrow = dp.xpw + (size_t)j * DI;
        const float* xrow = xr + ti * 769;
        for (int c = 0; c < DI; c += 4) {
          float4 w4 = *(const float4*)(wrow + c);
          acc = fmaf(w4.x, xrow[c], acc);
          acc = fmaf(w4.y, xrow[c + 1], acc);
          acc = fmaf(w4.z, xrow[c + 2], acc);
          acc = fmaf(w4.w, xrow[c + 3], acc);
        }
        dbls[ti * 56 + j] = acc;
      }
    }
  }
  __syncthreads();
  int tok = tid >> 4, dml = tid & 15;
  const float* db = dbls + tok * 56;
  for (int k = 0; k < 48; ++k) {
    int d = dml + k * 16;
    float acc = dp.dtb[d];
    const float* wr = dp.dtw + d * RNK;
#pragma unroll
    for (int r = 0; r < RNK; r += 4) {
      float4 w4 = *(const float4*)(wr + r);
      acc = fmaf(w4.x, db[r], acc);
      acc = fmaf(w4.y, db[r + 1], acc);
      acc = fmaf(w4.z, db[r + 2], acc);
      acc = fmaf(w4.w, db[r + 3], acc);
    }
    float sp = fmaxf(acc, 0.f) + log1pf(__expf(-fabsf(acc)));
    dt_all[(size_t)dir * (L_ * DI) + (size_t)(l0 + tok) * DI + d] = sp;
  }
  {
    int s = dml;
    B_all[dir * (L_ * DSTATE) + (l0 + tok) * DSTATE + s] = db[RNK + s];
    C_all[dir * (L_ * DSTATE) + (l0 + tok) * DSTATE + s] = db[RNK + DSTATE + s];
  }
}

// ---------------- Selective scan, chunk-parallel (3 phases) ----------------
// Phase A: per (dir, chunk, dgroup) run local recurrence from h=0.
// Emits h_local_end and P = exp(A * sum dt) per (dir,chunk,d,s).
__global__ __launch_bounds__(256) void k_scanA(const float* __restrict__ dt_all,
    const float* __restrict__ xc_all, const float* __restrict__ B_all,
    float* __restrict__ hend, float* __restrict__ Pbuf, AllParams P) {
  int dir = blockIdx.z, ch = blockIdx.y, d0 = blockIdx.x * 16;
  int tid = threadIdx.x, dl = tid >> 4, s = tid & 15;
  int l0 = ch * CH;
  const float* dt = dt_all + (size_t)dir * (L_ * DI);
  const float* xc = xc_all + (size_t)dir * (L_ * DI);
  const float* Bp = B_all + dir * (L_ * DSTATE);
  float Aval = -__expf(P.p[dir].Alog[(d0 + dl) * DSTATE + s]);
  __shared__ float dts[CH * 16], xcs[CH * 16], Bsh[CH * 16];
#pragma unroll
  for (int r = 0; r < CH * 16 / 256; ++r) {
    int idx = tid + r * 256;
    int i = idx >> 4, lj = idx & 15;
    dts[idx] = dt[(size_t)(l0 + i) * DI + d0 + lj];
    xcs[idx] = xc[(size_t)(l0 + i) * DI + d0 + lj];
    Bsh[idx] = Bp[(size_t)l0 * DSTATE + idx];
  }
  __syncthreads();
  float h = 0.f, sdt = 0.f;
  for (int ii = 0; ii < CH; ++ii) {
    float dtv = dts[ii * 16 + dl];
    float xv = xcs[ii * 16 + dl];
    float a = __expf(dtv * Aval);
    h = fmaf(a, h, dtv * xv * Bsh[ii * 16 + s]);
    sdt += dtv;
  }
  size_t o = ((size_t)(dir * NCH + ch) * 48 + blockIdx.x) * 256 + tid;
  hend[o] = h;
  Pbuf[o] = __expf(Aval * sdt);
}

// Phase B: sequential combine over the 16 chunks per (dir,d,s).
// In-place: hend[slot ch] is rewritten to h_START of chunk ch.
__global__ __launch_bounds__(256) void k_scanB(float* __restrict__ hend,
    const float* __restrict__ Pbuf) {
  int gid = blockIdx.x * 256 + threadIdx.x;      // 3*768*16 = 36864 threads
  int dir = gid / (DI * DSTATE);
  int rem = gid - dir * (DI * DSTATE);
  size_t base = (size_t)dir * NCH * (DI * DSTATE) + rem;
  float h = 0.f;
#pragma unroll
  for (int ch = 0; ch < NCH; ++ch) {
    size_t o = base + (size_t)ch * (DI * DSTATE);
    float p = Pbuf[o];
    float he = hend[o];
    hend[o] = h;                 // h_start for chunk ch
    h = fmaf(p, h, he);
  }
}

// Phase C: rerun local recurrence seeded with h_start, produce y.
__global__ __launch_bounds__(256) void k_scanC(const float* __restrict__ dt_all,
    const float* __restrict__ xc_all, const float* __restrict__ B_all,
    const float* __restrict__ C_all, const float* __restrict__ hstart,
    float* __restrict__ y_all, AllParams P) {
  int dir = blockIdx.z, ch = blockIdx.y, d0 = blockIdx.x * 16;
  int tid = threadIdx.x, dl = tid >> 4, s = tid & 15;
  int l0 = ch * CH;
  const float* dt = dt_all + (size_t)dir * (L_ * DI);
  const float* xc = xc_all + (size_t)dir * (L_ * DI);
  const float* Bp = B_all + dir * (L_ * DSTATE);
  const float* Cp = C_all + dir * (L_ * DSTATE);
  float* yp = y_all + (size_t)dir * (L_ * DI);
  float Aval = -__expf(P.p[dir].Alog[(d0 + dl) * DSTATE + s]);
  __shared__ float dts[CH * 16], xcs[CH * 16], Bsh[CH * 16], Csh[CH * 16], ysh[CH * 16];
#pragma unroll
  for (int r = 0; r < CH * 16 / 256; ++r) {
    int idx = tid + r * 256;
    int i = idx >> 4, lj = idx & 15;
    dts[idx] = dt[(size_t)(l0 + i) * DI + d0 + lj];
    xcs[idx] = xc[(size_t)(l0 + i) * DI + d0 + lj];
    Bsh[idx] = Bp[(size_t)l0 * DSTATE + idx];
    Csh[idx] = Cp[(size_t)l0 * DSTATE + idx];
  }
  __syncthreads();
  float h = hstart[((size_t)(dir * NCH + ch) * 48 + blockIdx.x) * 256 + tid];
  for (int ii = 0; ii < CH; ++ii) {
    float dtv = dts[ii * 16 + dl];
    float xv = xcs[ii * 16 + dl];
    float a = __expf(dtv * Aval);
    h = fmaf(a, h, dtv * xv * Bsh[ii * 16 + s]);
    float p = h * Csh[ii * 16 + s];
    p += __shfl_xor(p, 8);
    p += __shfl_xor(p, 4);
    p += __shfl_xor(p, 2);
    p += __shfl_xor(p, 1);
    if (s == 0) ysh[ii * 16 + dl] = p;
  }
  __syncthreads();
#pragma unroll
  for (int r = 0; r < CH * 16 / 256; ++r) {
    int idx = tid + r * 256;
    int i = idx >> 4, lj = idx & 15;
    yp[(size_t)(l0 + i) * DI + d0 + lj] = ysh[idx];
  }
}

// ---------------- Gate + combine 3 directions -> ysum (L,768) ----------------
__global__ __launch_bounds__(256) void k_gate(const float* __restrict__ y_all,
    const float* __restrict__ xc_all, const float* __restrict__ xz,
    float* __restrict__ ysum, AllParams P) {
  int l = blockIdx.x;
  int lb = 2047 - l;
  int ls = ((l & 255) << 3) + (l >> 8);   // inv of slice perm
  const size_t DSZ = (size_t)L_ * DI;
  for (int dd = threadIdx.x; dd < DI; dd += 256) {
    float yf = y_all[0 * DSZ + (size_t)l * DI + dd] + xc_all[0 * DSZ + (size_t)l * DI + dd] * P.p[0].D[dd];
    float yb = y_all[1 * DSZ + (size_t)lb * DI + dd] + xc_all[1 * DSZ + (size_t)lb * DI + dd] * P.p[1].D[dd];
    float ys = y_all[2 * DSZ + (size_t)ls * DI + dd] + xc_all[2 * DSZ + (size_t)ls * DI + dd] * P.p[2].D[dd];
    float z = xz[(size_t)l * 1536 + DI + dd];
    ysum[(size_t)l * DI + dd] = (yf + yb + ys) * (z / (1.f + __expf(-z)));
  }
}

extern "C" void kernel_launch(void* const* d_in, const int* in_sizes, int n_in,
                              void* d_out, int out_size, void* d_ws, size_t ws_size,
                              hipStream_t stream) {
  const float* x = (const float*)d_in[0];
  const float* ln_g = (const float*)d_in[1];
  const float* ln_b = (const float*)d_in[2];
  const float* in_proj_w = (const float*)d_in[3];
  const float* out_proj_w = (const float*)d_in[4];
  AllParams P;
  for (int dir = 0; dir < 3; ++dir) {
    int base = 5 + dir * 7;
    P.p[dir].cw  = (const float*)d_in[base + 0];
    P.p[dir].cb  = (const float*)d_in[base + 1];
    P.p[dir].xpw = (const float*)d_in[base + 2];
    P.p[dir].dtw = (const float*)d_in[base + 3];
    P.p[dir].dtb = (const float*)d_in[base + 4];
    P.p[dir].Alog= (const float*)d_in[base + 5];
    P.p[dir].D   = (const float*)d_in[base + 6];
  }
  float* ws = (float*)d_ws;
  const size_t SZ_XN = (size_t)L_ * CDIM;
  const size_t SZ_XZ = (size_t)L_ * 1536;
  const size_t SZ_DI = (size_t)L_ * DI;
  const size_t SZ_BS = (size_t)L_ * DSTATE;
  const size_t SZ_H  = (size_t)3 * NCH * DI * DSTATE;   // 589824
  float* xn    = ws;
  float* xz    = xn + SZ_XN;
  float* xc_a  = xz + SZ_XZ;
  float* dt_a  = xc_a + 3 * SZ_DI;
  float* B_a   = dt_a + 3 * SZ_DI;
  float* C_a   = B_a + 3 * SZ_BS;
  float* y_a   = C_a + 3 * SZ_BS;
  float* ysum  = y_a + 3 * SZ_DI;
  float* hend  = ysum + SZ_DI;
  float* Pbuf  = hend + SZ_H;

  k_ln<<<L_, 256, 0, stream>>>(x, ln_g, ln_b, xn);
  k_gemm<false><<<dim3(1536 / 64, L_ / 64), 256, 0, stream>>>(
      xn, in_proj_w, xz, nullptr, L_, 1536, CDIM);
  k_conv<<<dim3(L_ * 3, 3), 256, 0, stream>>>(xz, xc_a, P);
  k_xproj<<<dim3(L_ / 16, 3), 256, 0, stream>>>(xc_a, dt_a, B_a, C_a, P);
  k_scanA<<<dim3(48, NCH, 3), 256, 0, stream>>>(dt_a, xc_a, B_a, hend, Pbuf, P);
  k_scanB<<<144, 256, 0, stream>>>(hend, Pbuf);
  k_scanC<<<dim3(48, NCH, 3), 256, 0, stream>>>(dt_a, xc_a, B_a, C_a, hend, y_a, P);
  k_gate<<<L_, 256, 0, stream>>>(y_a, xc_a, xz, ysum, P);
  k_gemm<true><<<dim3(CDIM / 64, L_ / 64), 256, 0, stream>>>(
      ysum, out_proj_w, (float*)d_out, x, L_, CDIM, DI);
}

// Round 3
// 278.240 us; speedup vs baseline: 2.2779x; 1.2165x over previous
//
#include <hip/hip_runtime.h>
#include <math.h>

#define L_ 2048
#define CDIM 384
#define DI 768
#define DSTATE 16
#define RNK 24
#define NCH 64
#define CH 32

struct DirParams { const float *cw, *cb, *xpw, *dtw, *dtb, *Alog, *D; };
struct AllParams { DirParams p[3]; };

__device__ __forceinline__ int pmap(int dir, int l) {
  if (dir == 0) return l;
  if (dir == 1) return 2047 - l;
  return ((l & 7) << 8) + (l >> 3);   // slice perm: (l%8)*256 + l/8
}

// ---------------- LayerNorm: x (C,L) -> xn (L,C) ----------------
__global__ __launch_bounds__(256) void k_ln(const float* __restrict__ x,
    const float* __restrict__ g, const float* __restrict__ b,
    float* __restrict__ xn) {
  int l = blockIdx.x, tid = threadIdx.x;
  __shared__ float vals[CDIM];
  __shared__ float red[4];
  __shared__ float mu_s, rstd_s;
  float s = 0.f;
  for (int c = tid; c < CDIM; c += 256) {
    float v = x[(size_t)c * L_ + l];
    vals[c] = v; s += v;
  }
  for (int o = 32; o; o >>= 1) s += __shfl_down(s, o);
  int wid = tid >> 6, lane = tid & 63;
  if (lane == 0) red[wid] = s;
  __syncthreads();
  if (tid == 0) mu_s = (red[0] + red[1] + red[2] + red[3]) / (float)CDIM;
  __syncthreads();
  float mu = mu_s;
  float s2 = 0.f;
  for (int c = tid; c < CDIM; c += 256) { float v = vals[c] - mu; s2 += v * v; }
  for (int o = 32; o; o >>= 1) s2 += __shfl_down(s2, o);
  if (lane == 0) red[wid] = s2;
  __syncthreads();
  if (tid == 0) rstd_s = rsqrtf((red[0] + red[1] + red[2] + red[3]) / (float)CDIM + 1e-5f);
  __syncthreads();
  float rstd = rstd_s;
  for (int c = tid; c < CDIM; c += 256)
    xn[(size_t)l * CDIM + c] = (vals[c] - mu) * rstd * g[c] + b[c];
}

// ---------------- Tiled fp32 GEMM: C[m][n] = sum_k A[m][k]*W[n][k] ----------------
template <bool TRANS_OUT>
__global__ __launch_bounds__(256) void k_gemm(const float* __restrict__ A,
    const float* __restrict__ W, float* __restrict__ Cout,
    const float* __restrict__ resid, int M, int N, int K) {
  __shared__ float As[16][65];
  __shared__ float Bs[16][65];
  int m0 = blockIdx.y * 64, n0 = blockIdx.x * 64;
  int tid = threadIdx.x;
  int lr = tid >> 2;           // 0..63
  int lk = (tid & 3) << 2;     // 0,4,8,12
  int tm = (tid >> 4) << 2;    // 0..60
  int tn = (tid & 15) << 2;    // 0..60
  float acc[4][4] = {};
  for (int k0 = 0; k0 < K; k0 += 16) {
    float4 a = *(const float4*)(A + (size_t)(m0 + lr) * K + k0 + lk);
    float4 w = *(const float4*)(W + (size_t)(n0 + lr) * K + k0 + lk);
    As[lk + 0][lr] = a.x; As[lk + 1][lr] = a.y; As[lk + 2][lr] = a.z; As[lk + 3][lr] = a.w;
    Bs[lk + 0][lr] = w.x; Bs[lk + 1][lr] = w.y; Bs[lk + 2][lr] = w.z; Bs[lk + 3][lr] = w.w;
    __syncthreads();
#pragma unroll
    for (int kk = 0; kk < 16; ++kk) {
      float av[4], bv[4];
#pragma unroll
      for (int i = 0; i < 4; ++i) av[i] = As[kk][tm + i];
#pragma unroll
      for (int j = 0; j < 4; ++j) bv[j] = Bs[kk][tn + j];
#pragma unroll
      for (int i = 0; i < 4; ++i)
#pragma unroll
        for (int j = 0; j < 4; ++j) acc[i][j] = fmaf(av[i], bv[j], acc[i][j]);
    }
    __syncthreads();
  }
  if (!TRANS_OUT) {
#pragma unroll
    for (int i = 0; i < 4; ++i)
#pragma unroll
      for (int j = 0; j < 4; ++j)
        Cout[(size_t)(m0 + tm + i) * N + n0 + tn + j] = acc[i][j];
  } else {
#pragma unroll
    for (int i = 0; i < 4; ++i)
#pragma unroll
      for (int j = 0; j < 4; ++j) {
        size_t idx = (size_t)(n0 + tn + j) * M + (m0 + tm + i);
        Cout[idx] = acc[i][j] + resid[idx];
      }
  }
}

// ---------------- Conv(4, causal, depthwise) + SiLU, per direction ----------------
__global__ __launch_bounds__(256) void k_conv(const float* __restrict__ xz,
    float* __restrict__ xc_all, AllParams P) {
  int dir = blockIdx.y;
  int bx = blockIdx.x;
  int l = bx / 3, dch = bx % 3;
  int d = dch * 256 + threadIdx.x;
  const DirParams& dp = P.p[dir];
  float4 w = *(const float4*)(dp.cw + d * 4);
  float wv[4] = {w.x, w.y, w.z, w.w};
  float acc = dp.cb[d];
#pragma unroll
  for (int k = 0; k < 4; ++k) {
    int ls = l - 3 + k;
    if (ls >= 0) acc = fmaf(wv[k], xz[(size_t)pmap(dir, ls) * 1536 + d], acc);
  }
  float sv = acc / (1.f + __expf(-acc));
  xc_all[(size_t)dir * (L_ * DI) + (size_t)l * DI + d] = sv;
}

// ---------------- x-proj (768->56) + dt-proj (24->768) + softplus ----------------
__global__ __launch_bounds__(256) void k_xproj(const float* __restrict__ xc_all,
    float* __restrict__ dt_all, float* __restrict__ B_all, float* __restrict__ C_all,
    AllParams P) {
  int dir = blockIdx.y;
  int l0 = blockIdx.x * 16;
  const DirParams& dp = P.p[dir];
  const float* xc = xc_all + (size_t)dir * (L_ * DI) + (size_t)l0 * DI;
  __shared__ float xr[16 * 769];
  __shared__ float dbls[16 * 56];
  int tid = threadIdx.x;
  for (int idx = tid; idx < 16 * DI; idx += 256) {
    int t = idx / DI, c = idx - t * DI;
    xr[t * 769 + c] = xc[idx];
  }
  __syncthreads();
  {
    int ti = tid & 15, jg = tid >> 4;
    for (int j0 = 0; j0 < 64; j0 += 16) {
      int j = j0 + jg;
      if (j < 56) {
        float acc = 0.f;
        const float* wrow = dp.xpw + (size_t)j * DI;
        const float* xrow = xr + ti * 769;
        for (int c = 0; c < DI; c += 4) {
          float4 w4 = *(const float4*)(wrow + c);
          acc = fmaf(w4.x, xrow[c], acc);
          acc = fmaf(w4.y, xrow[c + 1], acc);
          acc = fmaf(w4.z, xrow[c + 2], acc);
          acc = fmaf(w4.w, xrow[c + 3], acc);
        }
        dbls[ti * 56 + j] = acc;
      }
    }
  }
  __syncthreads();
  int tok = tid >> 4, dml = tid & 15;
  const float* db = dbls + tok * 56;
  for (int k = 0; k < 48; ++k) {
    int d = dml + k * 16;
    float acc = dp.dtb[d];
    const float* wr = dp.dtw + d * RNK;
#pragma unroll
    for (int r = 0; r < RNK; r += 4) {
      float4 w4 = *(const float4*)(wr + r);
      acc = fmaf(w4.x, db[r], acc);
      acc = fmaf(w4.y, db[r + 1], acc);
      acc = fmaf(w4.z, db[r + 2], acc);
      acc = fmaf(w4.w, db[r + 3], acc);
    }
    float sp = fmaxf(acc, 0.f) + log1pf(__expf(-fabsf(acc)));
    dt_all[(size_t)dir * (L_ * DI) + (size_t)(l0 + tok) * DI + d] = sp;
  }
  {
    int s = dml;
    B_all[dir * (L_ * DSTATE) + (l0 + tok) * DSTATE + s] = db[RNK + s];
    C_all[dir * (L_ * DSTATE) + (l0 + tok) * DSTATE + s] = db[RNK + DSTATE + s];
  }
}

// ---------------- Selective scan, chunk-parallel, d-per-thread ----------------
// Thread <-> (dir, chunk, d); 16 states live in registers; no shuffles.
// Phase A: local recurrence from h=0 -> hend[dir][ch][d][s], P=exp(A*sum dt).
__global__ __launch_bounds__(256) void k_scanA(const float* __restrict__ dt_all,
    const float* __restrict__ xc_all, const float* __restrict__ B_all,
    float* __restrict__ hend, float* __restrict__ Pbuf, AllParams P) {
  int dir = blockIdx.z, ch = blockIdx.y;
  int d = blockIdx.x * 256 + threadIdx.x;
  int l0 = ch * CH;
  const float* dt = dt_all + (size_t)dir * (L_ * DI);
  const float* xc = xc_all + (size_t)dir * (L_ * DI);
  __shared__ float Bsh[CH * DSTATE];
  for (int t = threadIdx.x; t < CH * DSTATE; t += 256)
    Bsh[t] = B_all[(size_t)(dir * L_ + l0) * DSTATE + t];
  float Av[16];
#pragma unroll
  for (int r = 0; r < 4; ++r) {
    float4 q = *(const float4*)(P.p[dir].Alog + (size_t)d * DSTATE + r * 4);
    Av[r * 4 + 0] = -__expf(q.x); Av[r * 4 + 1] = -__expf(q.y);
    Av[r * 4 + 2] = -__expf(q.z); Av[r * 4 + 3] = -__expf(q.w);
  }
  __syncthreads();
  float h[16];
#pragma unroll
  for (int s = 0; s < 16; ++s) h[s] = 0.f;
  float sdt = 0.f;
  float dtv = dt[(size_t)l0 * DI + d];
  float xv  = xc[(size_t)l0 * DI + d];
  for (int ii = 0; ii < CH; ++ii) {
    float dtn = 0.f, xvn = 0.f;
    if (ii + 1 < CH) {                       // 1-deep prefetch pipeline
      dtn = dt[(size_t)(l0 + ii + 1) * DI + d];
      xvn = xc[(size_t)(l0 + ii + 1) * DI + d];
    }
    float dtx = dtv * xv;
    sdt += dtv;
    const float* Bi = Bsh + ii * DSTATE;
#pragma unroll
    for (int s = 0; s < 16; ++s)
      h[s] = fmaf(__expf(dtv * Av[s]), h[s], dtx * Bi[s]);
    dtv = dtn; xv = xvn;
  }
  size_t o = (((size_t)(dir * NCH + ch)) * DI + d) * DSTATE;
#pragma unroll
  for (int s = 0; s < 16; ++s) {
    hend[o + s] = h[s];
    Pbuf[o + s] = __expf(Av[s] * sdt);
  }
}

// Phase B: sequential combine over the 64 chunks per (dir,d,s).
// In-place: hend[slot ch] becomes h_START of chunk ch.
__global__ __launch_bounds__(256) void k_scanB(float* __restrict__ hend,
    const float* __restrict__ Pbuf) {
  int gid = blockIdx.x * 256 + threadIdx.x;      // 3*768*16 = 36864 threads
  int dir = gid / (DI * DSTATE);
  int rem = gid - dir * (DI * DSTATE);
  size_t base = (size_t)dir * NCH * (DI * DSTATE) + rem;
  float h = 0.f;
#pragma unroll 8
  for (int ch = 0; ch < NCH; ++ch) {
    size_t o = base + (size_t)ch * (DI * DSTATE);
    float p = Pbuf[o];
    float he = hend[o];
    hend[o] = h;                 // h_start for chunk ch
    h = fmaf(p, h, he);
  }
}

// Phase C: rerun recurrence seeded with h_start, emit y (thread-local dot over s).
__global__ __launch_bounds__(256) void k_scanC(const float* __restrict__ dt_all,
    const float* __restrict__ xc_all, const float* __restrict__ B_all,
    const float* __restrict__ C_all, const float* __restrict__ hstart,
    float* __restrict__ y_all, AllParams P) {
  int dir = blockIdx.z, ch = blockIdx.y;
  int d = blockIdx.x * 256 + threadIdx.x;
  int l0 = ch * CH;
  const float* dt = dt_all + (size_t)dir * (L_ * DI);
  const float* xc = xc_all + (size_t)dir * (L_ * DI);
  float* yp = y_all + (size_t)dir * (L_ * DI);
  __shared__ float Bsh[CH * DSTATE];
  __shared__ float Csh[CH * DSTATE];
  for (int t = threadIdx.x; t < CH * DSTATE; t += 256) {
    Bsh[t] = B_all[(size_t)(dir * L_ + l0) * DSTATE + t];
    Csh[t] = C_all[(size_t)(dir * L_ + l0) * DSTATE + t];
  }
  float Av[16];
#pragma unroll
  for (int r = 0; r < 4; ++r) {
    float4 q = *(const float4*)(P.p[dir].Alog + (size_t)d * DSTATE + r * 4);
    Av[r * 4 + 0] = -__expf(q.x); Av[r * 4 + 1] = -__expf(q.y);
    Av[r * 4 + 2] = -__expf(q.z); Av[r * 4 + 3] = -__expf(q.w);
  }
  float h[16];
  size_t o = (((size_t)(dir * NCH + ch)) * DI + d) * DSTATE;
#pragma unroll
  for (int r = 0; r < 4; ++r) {
    float4 q = *(const float4*)(hstart + o + r * 4);
    h[r * 4 + 0] = q.x; h[r * 4 + 1] = q.y; h[r * 4 + 2] = q.z; h[r * 4 + 3] = q.w;
  }
  __syncthreads();
  float dtv = dt[(size_t)l0 * DI + d];
  float xv  = xc[(size_t)l0 * DI + d];
  for (int ii = 0; ii < CH; ++ii) {
    float dtn = 0.f, xvn = 0.f;
    if (ii + 1 < CH) {
      dtn = dt[(size_t)(l0 + ii + 1) * DI + d];
      xvn = xc[(size_t)(l0 + ii + 1) * DI + d];
    }
    float dtx = dtv * xv;
    const float* Bi = Bsh + ii * DSTATE;
    const float* Ci = Csh + ii * DSTATE;
    float y = 0.f;
#pragma unroll
    for (int s = 0; s < 16; ++s) {
      h[s] = fmaf(__expf(dtv * Av[s]), h[s], dtx * Bi[s]);
      y = fmaf(h[s], Ci[s], y);
    }
    yp[(size_t)(l0 + ii) * DI + d] = y;
    dtv = dtn; xv = xvn;
  }
}

// ---------------- Gate + combine 3 directions -> ysum (L,768) ----------------
__global__ __launch_bounds__(256) void k_gate(const float* __restrict__ y_all,
    const float* __restrict__ xc_all, const float* __restrict__ xz,
    float* __restrict__ ysum, AllParams P) {
  int l = blockIdx.x;
  int lb = 2047 - l;
  int ls = ((l & 255) << 3) + (l >> 8);   // inv of slice perm
  const size_t DSZ = (size_t)L_ * DI;
  for (int dd = threadIdx.x; dd < DI; dd += 256) {
    float yf = y_all[0 * DSZ + (size_t)l * DI + dd] + xc_all[0 * DSZ + (size_t)l * DI + dd] * P.p[0].D[dd];
    float yb = y_all[1 * DSZ + (size_t)lb * DI + dd] + xc_all[1 * DSZ + (size_t)lb * DI + dd] * P.p[1].D[dd];
    float ys = y_all[2 * DSZ + (size_t)ls * DI + dd] + xc_all[2 * DSZ + (size_t)ls * DI + dd] * P.p[2].D[dd];
    float z = xz[(size_t)l * 1536 + DI + dd];
    ysum[(size_t)l * DI + dd] = (yf + yb + ys) * (z / (1.f + __expf(-z)));
  }
}

extern "C" void kernel_launch(void* const* d_in, const int* in_sizes, int n_in,
                              void* d_out, int out_size, void* d_ws, size_t ws_size,
                              hipStream_t stream) {
  const float* x = (const float*)d_in[0];
  const float* ln_g = (const float*)d_in[1];
  const float* ln_b = (const float*)d_in[2];
  const float* in_proj_w = (const float*)d_in[3];
  const float* out_proj_w = (const float*)d_in[4];
  AllParams P;
  for (int dir = 0; dir < 3; ++dir) {
    int base = 5 + dir * 7;
    P.p[dir].cw  = (const float*)d_in[base + 0];
    P.p[dir].cb  = (const float*)d_in[base + 1];
    P.p[dir].xpw = (const float*)d_in[base + 2];
    P.p[dir].dtw = (const float*)d_in[base + 3];
    P.p[dir].dtb = (const float*)d_in[base + 4];
    P.p[dir].Alog= (const float*)d_in[base + 5];
    P.p[dir].D   = (const float*)d_in[base + 6];
  }
  float* ws = (float*)d_ws;
  const size_t SZ_XN = (size_t)L_ * CDIM;             // 786432
  const size_t SZ_XZ = (size_t)L_ * 1536;             // 3145728
  const size_t SZ_DI = (size_t)L_ * DI;               // 1572864
  const size_t SZ_BS = (size_t)L_ * DSTATE;           // 32768
  const size_t SZ_H  = (size_t)3 * NCH * DI * DSTATE; // 2359296 == SZ_XN + SZ_DI
  // Aliasing plan (lifetime-checked):
  //   hend aliases [xn][ysum]: xn dead after gemm1 (before scanA);
  //     ysum written by k_gate only after scanC has consumed hend.
  //   Pbuf aliases y_a head: P dead after scanB; scanC then overwrites y_a.
  float* xn   = ws;                   // dead after gemm1
  float* ysum = ws + SZ_XN;           // written by k_gate
  float* hend = ws;                   // SZ_H, overlays xn+ysum exactly
  float* xz   = ws + SZ_H;
  float* xc_a = xz + SZ_XZ;
  float* dt_a = xc_a + 3 * SZ_DI;
  float* B_a  = dt_a + 3 * SZ_DI;
  float* C_a  = B_a + 3 * SZ_BS;
  float* y_a  = C_a + 3 * SZ_BS;
  float* Pbuf = y_a;                  // first SZ_H floats of y_a

  k_ln<<<L_, 256, 0, stream>>>(x, ln_g, ln_b, xn);
  k_gemm<false><<<dim3(1536 / 64, L_ / 64), 256, 0, stream>>>(
      xn, in_proj_w, xz, nullptr, L_, 1536, CDIM);
  k_conv<<<dim3(L_ * 3, 3), 256, 0, stream>>>(xz, xc_a, P);
  k_xproj<<<dim3(L_ / 16, 3), 256, 0, stream>>>(xc_a, dt_a, B_a, C_a, P);
  k_scanA<<<dim3(DI / 256, NCH, 3), 256, 0, stream>>>(dt_a, xc_a, B_a, hend, Pbuf, P);
  k_scanB<<<144, 256, 0, stream>>>(hend, Pbuf);
  k_scanC<<<dim3(DI / 256, NCH, 3), 256, 0, stream>>>(dt_a, xc_a, B_a, C_a, hend, y_a, P);
  k_gate<<<L_, 256, 0, stream>>>(y_a, xc_a, xz, ysum, P);
  k_gemm<true><<<dim3(CDIM / 64, L_ / 64), 256, 0, stream>>>(
      ysum, out_proj_w, (float*)d_out, x, L_, CDIM, DI);
}